// Round 20
// baseline (51.599 us; speedup 1.0000x reference)
//
#include <hip/hip_runtime.h>
#include <hip/hip_bf16.h>

#define HH 192
#define WW 192
#define HOUT 190
#define NCH 64
#define W2_N (64 * 9 * 64)

typedef __attribute__((ext_vector_type(8))) short bf16x8;
typedef __attribute__((ext_vector_type(4))) float f32x4;

static __device__ __forceinline__ ushort f2bf(float f) {
    __hip_bfloat16 h = __float2bfloat16(f);   // RNE
    return *reinterpret_cast<ushort*>(&h);
}

// W2[o][tap][c] = sum_t (conn[o*16+t]==c) * w[(o*16+t)*9 + tap], bf16.
__global__ __launch_bounds__(256) void build_w2(const float* __restrict__ w,
                                                const int* __restrict__ conn,
                                                ushort* __restrict__ w2) {
    int idx = blockIdx.x * 256 + threadIdx.x;
    if (idx >= W2_N) return;
    int o = idx / 576, rem = idx - o * 576, tap = rem >> 6, c = rem & 63;
    float s = 0.f;
    #pragma unroll
    for (int t = 0; t < 16; ++t) {
        int k = o * 16 + t;
        if (conn[k] == c) s += w[k * 9 + tap];
    }
    w2[idx] = f2bf(s);
}

// Dense 64->64 3x3 conv via mfma_f32_16x16x32_bf16, tap-outer implicit GEMM.
// Block: 8 output rows x 16 cols x 64 outch. 4 waves, wave w = outch 16w..16w+15.
// LDS x-tile: [10 rows][18 cols][72 ch-slots] bf16 (col stride 144 B).
// Staging: lane = spatial (3 rows x 18 cols, 54 lanes), channel uniform per
// instr -> 3-segment loads; wave w stages channels 16w..16w+15 (R19 bug fix).
__global__ __launch_bounds__(256, 4) void scm_mfma(
    const float* __restrict__ x,
    const ushort* __restrict__ w2,
    const float* __restrict__ bias,
    float* __restrict__ out)
{
    __shared__ ushort xt[10 * 18 * 72];   // 25,920 B

    const int tid  = threadIdx.x;
    const int lane = tid & 63;
    const int wv   = tid >> 6;
    const int col  = lane & 15;           // A-frag m (pixel col) / B-frag n
    const int g    = lane >> 4;           // k-subgroup

    const int tileid = blockIdx.x;        // 0..287
    const int b      = blockIdx.y;
    const int ti0 = (tileid / 12) * 8;    // 24 row tiles
    const int tj0 = (tileid % 12) * 16;   // 12 col tiles

    // ---- staging: spatial-lane gather, wave-sliced channels
    {
        const int srr  = lane / 18;       // 0..2 (lanes 54..63 idle)
        const int scol = lane - srr * 18; // 0..17
        const bool act = lane < 54;
        int gc = tj0 + scol; if (gc > 191) gc = 191;
        #pragma unroll
        for (int j = 0; j < 16; ++j) {
            const int c = wv * 16 + j;    // wave-uniform channel, full 0..63 coverage
            const float* xc = x + ((size_t)(b * NCH + c)) * (HH * WW);
            #pragma unroll
            for (int trio = 0; trio < 4; ++trio) {
                const int lrow = trio * 3 + srr;          // 0..11
                if (act && lrow < 10) {
                    int gr = ti0 + lrow; if (gr > 191) gr = 191;
                    xt[(lrow * 18 + scol) * 72 + c] = f2bf(xc[gr * WW + gc]);
                }
            }
        }
    }
    __syncthreads();

    // ---- compute
    f32x4 acc[8];
    #pragma unroll
    for (int i = 0; i < 8; ++i) acc[i] = (f32x4){0.f, 0.f, 0.f, 0.f};

    // B base: W2[(16wv+col)][tap][s*32+8g..+7]
    const ushort* bp  = w2 + (16 * wv + col) * 576 + g * 8;
    // A base: xt[(R*18 + col + kw)*72 + s*32 + 8g]
    const ushort* ap0 = &xt[col * 72 + g * 8];

    #pragma unroll
    for (int s = 0; s < 2; ++s) {
        #pragma unroll
        for (int kw = 0; kw < 3; ++kw) {
            const bf16x8 B0 = *(const bf16x8*)(bp + (0 * 3 + kw) * 64 + s * 32);
            const bf16x8 B1 = *(const bf16x8*)(bp + (1 * 3 + kw) * 64 + s * 32);
            const bf16x8 B2 = *(const bf16x8*)(bp + (2 * 3 + kw) * 64 + s * 32);
            bf16x8 f[10];
            #pragma unroll
            for (int R = 0; R < 10; ++R)
                f[R] = *(const bf16x8*)(ap0 + (R * 18 + kw) * 72 + s * 32);
            #pragma unroll
            for (int Mt = 0; Mt < 8; ++Mt) {
                acc[Mt] = __builtin_amdgcn_mfma_f32_16x16x32_bf16(f[Mt],     B0, acc[Mt], 0, 0, 0);
                acc[Mt] = __builtin_amdgcn_mfma_f32_16x16x32_bf16(f[Mt + 1], B1, acc[Mt], 0, 0, 0);
                acc[Mt] = __builtin_amdgcn_mfma_f32_16x16x32_bf16(f[Mt + 2], B2, acc[Mt], 0, 0, 0);
            }
        }
    }

    // ---- epilogue: D row = 4g+reg -> pixel col tj0+4g+reg; D col = lane&15 -> o.
    const int o = 16 * wv + col;
    const float bv = bias[o];
    #pragma unroll
    for (int Mt = 0; Mt < 8; ++Mt) {
        int row = ti0 + Mt;
        if (row < HOUT) {
            int cj = tj0 + 4 * g;
            float* rp = out + ((size_t)(b * NCH + o) * HOUT + row) * HOUT + cj;
            float v0 = acc[Mt][0] + bv, v1 = acc[Mt][1] + bv;
            float v2 = acc[Mt][2] + bv, v3 = acc[Mt][3] + bv;
            if (cj + 3 < HOUT) {
                *(float2*)(rp)     = make_float2(v0, v1);
                *(float2*)(rp + 2) = make_float2(v2, v3);
            } else {
                if (cj     < HOUT) rp[0] = v0;
                if (cj + 1 < HOUT) rp[1] = v1;
                if (cj + 2 < HOUT) rp[2] = v2;
                if (cj + 3 < HOUT) rp[3] = v3;
            }
        }
    }
}

extern "C" void kernel_launch(void* const* d_in, const int* in_sizes, int n_in,
                              void* d_out, int out_size, void* d_ws, size_t ws_size,
                              hipStream_t stream) {
    const float* x       = (const float*)d_in[0];
    const float* weight  = (const float*)d_in[1];
    const float* bias    = (const float*)d_in[2];
    const int*   conn_in = (const int*)d_in[3];
    // d_in[4] = conn_out (implicit: k -> k/16)

    ushort* w2 = (ushort*)d_ws;   // 73,728 B

    build_w2<<<dim3((W2_N + 255) / 256), dim3(256), 0, stream>>>(weight, conn_in, w2);

    dim3 grid(288, 4);            // 24x12 pixel tiles x 4 batches
    scm_mfma<<<grid, dim3(256), 0, stream>>>(x, w2, bias, (float*)d_out);
}